// Round 8
// baseline (340.104 us; speedup 1.0000x reference)
//
#include <hip/hip_runtime.h>
#include <stdint.h>

// ---------------------------------------------------------------------------
// MultiMonotoneHollowConv, round 9: y1m_k async-stage restructure (T14).
//   phase A prep_k : x1t transpose  |  weight blobs  |  bias sumsq partials
//   phase B y1m_k  : Y1 MFMA (+1 block reduces sumsq partials -> SUM)
//   phase C outs_k : out0 (LDS-staged)  |  out1 (de-staged, direct global)
// y1m_k changes (math bit-identical):
//   1. issue-early/write-late x0 staging: float2 loads -> packed u32 regs ->
//      W11 MFMA section -> ds_write -> barrier -> W10 (HBM latency hidden).
//   2. lane remap [r][cp][chp]: 64B-contiguous float2 loads per ch; LDS
//      writes 2 lanes/bank (free) vs old 4-way conflict.
//   3. border-only zero-fill (216 uint4, disjoint from staged cells) ->
//      first __syncthreads deleted.
// MFMA frag layouts (gfx950, HW-verified per guide):
//   A[m=lane&15][k=quad*8+j], B[k=quad*8+j][n=lane&15], D: row m=quad*4+reg,
//   col n=lane&15.
// ---------------------------------------------------------------------------

using short8 = __attribute__((ext_vector_type(8))) short;
using f32x4  = __attribute__((ext_vector_type(4))) float;

#define B_ 16

// workspace byte offsets (total ~34.46 MB; must stay < ~35.1 MB proven safe)
static constexpr size_t Y1T_OFF  = 0;                        // [16][130][132][32] bf16
static constexpr size_t Y1T_ROWB = 132 * 64;                 // 8448 B per (b,iy) row
static constexpr size_t X1T_OFF  = (size_t)16 * 130 * 132 * 64;        // 17,571,840
static constexpr size_t AB0_OFF  = X1T_OFF + (size_t)16 * 128 * 128 * 64; // +16,777,216
static constexpr size_t AB1_OFF  = AB0_OFF + 24 * 1024;     // blob0: 24 chunks
static constexpr size_t SUM_OFF  = AB1_OFF + 20 * 1024;     // blob1: 10 chunks x 2
static constexpr size_t AB2_OFF  = SUM_OFF + 1024;          // y1 fwd weights: 56 chunks
static constexpr size_t PART_OFF = AB2_OFF + 56 * 1024;     // sumsq partials: 384 f32

__device__ __forceinline__ uint32_t bf16rne(float v) {
  uint32_t u = __float_as_uint(v);
  return (u + 0x7fffu + ((u >> 16) & 1u)) >> 16;
}
__device__ __forceinline__ uint32_t packbf(float lo, float hi) {
  return bf16rne(lo) | (bf16rne(hi) << 16);
}
__device__ __forceinline__ f32x4 mfma16(short8 a, short8 b, f32x4 c) {
  return __builtin_amdgcn_mfma_f32_16x16x32_bf16(a, b, c, 0, 0, 0);
}
// XCD-aware swizzle: nblk % 8 == 0; each XCD gets a contiguous chunk.
__device__ __forceinline__ int xcd_swz(int bid, int chunk) {
  return (bid & 7) * chunk + (bid >> 3);
}

// ---------------------------------------------------------------------------
// prep_k: raw [0,2048) x1t | [2048,2248) blob | [2248,2312) sumsq b0 (64 blk,
// per-wave partial slots 0..255) | [2312,2344) sumsq b1 (slots 256..383).
// All writes to disjoint regions -> no intra-kernel cross-block hazards.
__global__ __launch_bounds__(256) void prep_k(const float* __restrict__ x1,
                                              const float* __restrict__ W00,
                                              const float* __restrict__ W10,
                                              const float* __restrict__ W11,
                                              const float* __restrict__ b0,
                                              const float* __restrict__ b1,
                                              char* __restrict__ ws) {
  __shared__ __align__(16) uint16_t tmp[128 * 32];   // x1t path only (8 KB)
  int raw = blockIdx.x, tid = threadIdx.x;

  if (raw < 2048) {
    // --- x1t[b][r][c][ch] = bf16(x1[b][ch][r][c]) ---
    int b = raw >> 7, r = raw & 127;
    for (int e = tid; e < 4096; e += 256) {
      int ch = e >> 7, c = e & 127;
      float v = x1[((size_t)(b * 32 + ch) * 128 + r) * 128 + c];
      tmp[c * 32 + ch] = (uint16_t)bf16rne(v);
    }
    __syncthreads();
    char* dst = ws + X1T_OFF + ((size_t)(b * 128 + r) * 128) * 64;
    for (int e = tid; e < 512; e += 256)
      *(short8*)(dst + e * 16) = *(const short8*)((const char*)tmp + e * 16);
    return;
  }

  if (raw < 2248) {
    // --- weight blobs (exact A-fragment order, bf16) ---
    int e = (raw - 2048) * 256 + tid;
    if (e < 12288) {
      int chunk = e >> 9, le = e & 511, lane = le >> 3, j = le & 7;
      int q = lane >> 4, m = lane & 15;
      float val = 0.f;
      if (chunk < 13) {
        int t = 2 * chunk + (q >> 1);
        int n = ((q & 1) << 3) + j;
        if (t <= 24 && t != 12) {
          int dy = t / 5 - 2, dx = t % 5 - 2;
          for (int o = 0; o < 16; ++o) {
            const float* wm = W00 + (o * 16 + m) * 9;
            const float* wn = W00 + (o * 16 + n) * 9;
            for (int ay = 0; ay < 3; ++ay) {
              int ay2 = ay + dy; if ((unsigned)ay2 > 2u) continue;
              for (int ax = 0; ax < 3; ++ax) {
                int ax2 = ax + dx; if ((unsigned)ax2 > 2u) continue;
                val += wm[ay * 3 + ax] * wn[ay2 * 3 + ax2];
              }
            }
          }
        }
      } else if (chunk < 22) {
        int tap = chunk - 13;
        int o = ((lane >> 4) << 3) + j;      // k = q*8+j
        val = W10[(o * 16 + m) * 9 + tap];
      } else {
        int py = chunk - 22;
        int k = ((lane >> 4) << 3) + j;
        int par = k >> 4, n = k & 15;
        for (int o = 0; o < 32; ++o) {
          const float* wn = W10 + (o * 16 + n) * 9;
          const float* wm = W10 + (o * 16 + m) * 9;
          for (int by = 0; by < 3; ++by) {
            if ((py == 0) ? (by != 1) : (by == 1)) continue;
            for (int bx = 0; bx < 3; ++bx) {
              if ((par == 0) ? (bx != 1) : (bx == 1)) continue;
              val -= wn[by * 3 + bx] * wm[by * 3 + bx];
            }
          }
        }
      }
      ((uint16_t*)(ws + AB0_OFF))[chunk * 512 + lane * 8 + j] = (uint16_t)bf16rne(val);
    } else if (e < 12288 + 10240) {
      int e2 = e - 12288;
      int chunk = e2 >> 10, r = e2 & 1023, h = r >> 9, le = r & 511;
      int lane = le >> 3, j = le & 7;
      int m = h * 16 + (lane & 15);
      int kk = ((lane >> 4) << 3) + j;      // k = q*8+j
      float val = 0.f;
      if (chunk < 9) {
        val = W11[(kk * 32 + m) * 9 + chunk];      // o = kk, tap = chunk
      } else if ((kk >> 4) == h) {
        int np = kk & 15;
        float s = 0.f;
        for (int o = 0; o < 32; ++o)
          for (int t = 0; t < 9; ++t)
            s += W11[(o * 32 + m) * 9 + t] * W11[(o * 32 + h * 16 + np) * 9 + t];
        val = -s;
      }
      ((uint16_t*)(ws + AB1_OFF))[(chunk * 2 + h) * 512 + lane * 8 + j] = (uint16_t)bf16rne(val);
    } else if (e < 12288 + 10240 + 28672) {
      int e3 = e - 22528;
      int chunk = e3 >> 9, le = e3 & 511;
      int lane = le >> 3, j = le & 7;
      int q = lane >> 4, m = lane & 15;
      int k = q * 8 + j;
      int part;
      float val = 0.f;
      if (chunk < 36) {
        int t = chunk >> 2, h = (chunk >> 1) & 1;
        part = chunk & 1;
        int o = h * 16 + m;
        val = W11[(o * 32 + k) * 9 + t];           // fwd: A[m=o][k=ich]
      } else {
        int c2 = chunk - 36;
        int c5 = c2 >> 2, h = (c2 >> 1) & 1;
        part = c2 & 1;
        int tap = 2 * c5 + (k >> 4);
        int o = h * 16 + m;
        if (tap <= 8) val = W10[(o * 16 + (k & 15)) * 9 + tap];
      }
      uint32_t hi = bf16rne(val);
      uint16_t outv;
      if (part == 0) outv = (uint16_t)hi;
      else outv = (uint16_t)bf16rne(val - __uint_as_float(hi << 16));
      ((uint16_t*)(ws + AB2_OFF))[chunk * 512 + lane * 8 + j] = outv;
    }
    return;
  }

  // --- sumsq partials (write-only slots, no init / no atomics) ---
  float* part = (float*)(ws + PART_OFF);
  if (raw < 2312) {
    int blk = raw - 2248;                  // 64 blocks over b0 (1,048,576)
    float s = 0.f;
    for (int i = blk * 256 + tid; i < 1048576; i += 64 * 256) {
      float v = b0[i]; s += v * v;
    }
    #pragma unroll
    for (int off = 32; off > 0; off >>= 1) s += __shfl_down(s, off, 64);
    if ((tid & 63) == 0) part[blk * 4 + (tid >> 6)] = s;
  } else {
    int blk = raw - 2312;                  // 32 blocks over b1 (524,288)
    float s = 0.f;
    for (int i = blk * 256 + tid; i < 524288; i += 32 * 256) {
      float v = b1[i]; s += v * v;
    }
    #pragma unroll
    for (int off = 32; off > 0; off >>= 1) s += __shfl_down(s, off, 64);
    if ((tid & 63) == 0) part[256 + blk * 4 + (tid >> 6)] = s;
  }
}

// ---------------------------------------------------------------------------
// Y1 via MFMA: one block per (b, iy); 4 waves; 9 px-frags of 16 (130 used).
// LDS x0s: [ql 2][row 3][par 2][half-col 146][ch8] bf16 (col = 2h+p-3).
// x1 B-frags: DIRECT global reads from x1t (frag-order layout, L1-resident).
// Async stage: x0 loads -> packed regs -> W11 MFMAs -> ds_write -> barrier.
// Grid 2088: raw 2080 reduces sumsq partials -> SUM; 2081..2087 exit.
__global__ __launch_bounds__(256, 5) void y1m_k(const float* __restrict__ x0,
                                                char* __restrict__ ws) {
  __shared__ __align__(16) uint16_t x0s[2 * 3 * 2 * 146 * 8];   // 28,032 B
  int tid = threadIdx.x;
  if (blockIdx.x >= 2080) {
    if (blockIdx.x == 2080) {
      int lane = tid & 63, wvv = tid >> 6;
      const float* part = (const float*)(ws + PART_OFF);
      if (wvv == 0) {
        float s = part[lane * 4] + part[lane * 4 + 1] + part[lane * 4 + 2] + part[lane * 4 + 3];
        #pragma unroll
        for (int off = 32; off > 0; off >>= 1) s += __shfl_down(s, off, 64);
        if (lane == 0) ((float*)(ws + SUM_OFF))[0] = s;
      } else if (wvv == 1) {
        float s = part[256 + lane * 2] + part[256 + lane * 2 + 1];
        #pragma unroll
        for (int off = 32; off > 0; off >>= 1) s += __shfl_down(s, off, 64);
        if (lane == 0) ((float*)(ws + SUM_OFF))[1] = s;
      }
    }
    return;
  }
  int bid = xcd_swz(blockIdx.x, 260);          // 2080 work blocks
  int b = bid / 130, iy = bid % 130;

  { // zero ONLY never-written border cols (disjoint from staged cells ->
    // no barrier needed before the staging writes).
    // plane pl = ((ql*3+r)*2+p); p=1 staged hc in [1,128], p=0 in [2,129].
    uint4 z = make_uint4(0u, 0u, 0u, 0u);
    for (int zi = tid; zi < 216; zi += 256) {
      int pl = zi / 18, k = zi % 18;
      int hc = (pl & 1) ? (k == 0 ? 0 : k + 128) : (k < 2 ? k : k + 128);
      *(uint4*)((char*)x0s + (size_t)(pl * 146 + hc) * 16) = z;
    }
  }

  // ---- async stage phase 1: x0 rows 2iy-3..2iy-1 -> packed u32 regs ----
  // e = tid+it*256 over 3072 = [r 3][cp 128][chp 8]; per wave 8 chp x 8 cp
  // -> 64B-contiguous float2 loads per ch; writes later are 2 lanes/bank.
  uint32_t wlo[12], whi[12];
  {
    const float* x0b = x0 + (size_t)b * 1048576;
    #pragma unroll
    for (int it = 0; it < 12; ++it) {
      int e = tid + it * 256;
      int r = e >> 10, cp = (e >> 3) & 127, ch0 = (e & 7) * 2;
      int gy = 2 * iy + r - 3;
      float2 f0 = make_float2(0.f, 0.f), f1 = make_float2(0.f, 0.f);
      if ((unsigned)gy < 256u) {
        const float* rp = x0b + (size_t)ch0 * 65536 + (size_t)gy * 256 + 2 * cp;
        f0 = *(const float2*)rp;
        f1 = *(const float2*)(rp + 65536);
      }
      wlo[it] = packbf(f0.x, f1.x);   // col 2cp   -> plane p=1, hc=cp+1
      whi[it] = packbf(f0.y, f1.y);   // col 2cp+1 -> plane p=0, hc=cp+2
    }
  }

  int lane = tid & 63, wv = tid >> 6;
  int nn = lane & 15, q = lane >> 4, qh = q >> 1, ql = q & 1;
  const char* ab2 = ws + AB2_OFF;
  const char* x1tb = ws + X1T_OFF;

  f32x4 a00 = {0.f,0.f,0.f,0.f}, a01 = {0.f,0.f,0.f,0.f};
  f32x4 a10 = {0.f,0.f,0.f,0.f}, a11 = {0.f,0.f,0.f,0.f};
  f32x4 a20 = {0.f,0.f,0.f,0.f}, a21 = {0.f,0.f,0.f,0.f};
  const short8 z8 = {0,0,0,0,0,0,0,0};

  // --- W11 fwd (s1,p2): 9 taps, K=32 in-ch; B-frags direct from x1t.
  //     Runs while x0 stage loads are in flight (no LDS use). ---
  #pragma unroll
  for (int t = 0; t < 9; ++t) {
    const int ay = t / 3, ax = t % 3;
    const char* cb = ab2 + t * 4096 + lane * 16;
    short8 Ah0 = *(const short8*)(cb);
    short8 Al0 = *(const short8*)(cb + 1024);
    short8 Ah1 = *(const short8*)(cb + 2048);
    short8 Al1 = *(const short8*)(cb + 3072);
    int gy = iy + ay - 2;
    bool rowok = ((unsigned)gy < 128u);
    const char* rb = x1tb + ((size_t)(b * 128 + (rowok ? gy : 0))) * 8192 + q * 16;
    int c0 = (wv << 4) + nn + ax - 2;
    bool ok0 = rowok && ((unsigned)c0 < 128u);
    short8 B0 = *(const short8*)(rb + (size_t)(ok0 ? c0 : 0) * 64);
    if (!ok0) B0 = z8;
    int c1 = c0 + 64;
    bool ok1 = rowok && ((unsigned)c1 < 128u);
    short8 B1 = *(const short8*)(rb + (size_t)(ok1 ? c1 : 0) * 64);
    if (!ok1) B1 = z8;
    a00 = mfma16(Ah0, B0, a00); a00 = mfma16(Al0, B0, a00);
    a01 = mfma16(Ah1, B0, a01); a01 = mfma16(Al1, B0, a01);
    a10 = mfma16(Ah0, B1, a10); a10 = mfma16(Al0, B1, a10);
    a11 = mfma16(Ah1, B1, a11); a11 = mfma16(Al1, B1, a11);
    if (wv == 0) {
      int c2 = c0 + 128;
      bool ok2 = rowok && ((unsigned)c2 < 128u);
      short8 B2 = *(const short8*)(rb + (size_t)(ok2 ? c2 : 0) * 64);
      if (!ok2) B2 = z8;
      a20 = mfma16(Ah0, B2, a20); a20 = mfma16(Al0, B2, a20);
      a21 = mfma16(Ah1, B2, a21); a21 = mfma16(Al1, B2, a21);
    }
  }

  // ---- async stage phase 2: write packed x0 to LDS (2 lanes/bank) ----
  #pragma unroll
  for (int it = 0; it < 12; ++it) {
    int e = tid + it * 256;
    int r = e >> 10, cp = (e >> 3) & 127, ch0 = (e & 7) * 2;
    char* pbase = (char*)x0s + (size_t)(((ch0 >> 3) * 3 + r) * 2) * 2336 + (ch0 & 7) * 2;
    *(uint32_t*)(pbase + (size_t)(146 + cp + 1) * 16) = wlo[it];   // p=1 plane
    *(uint32_t*)(pbase + (size_t)(cp + 2) * 16)       = whi[it];   // p=0 plane
  }
  __syncthreads();   // x0s fully staged (border zeros + data)

  // --- W10 fwd (s2,p3): tap-pair chunks, k = qh*16 + ich ---
  #pragma unroll
  for (int c5 = 0; c5 < 5; ++c5) {
    const char* cb = ab2 + (36 + c5 * 4) * 1024 + lane * 16;
    short8 Ah0 = *(const short8*)(cb);
    short8 Al0 = *(const short8*)(cb + 1024);
    short8 Ah1 = *(const short8*)(cb + 2048);
    short8 Al1 = *(const short8*)(cb + 3072);
    int tl = 2 * c5 + qh; if (tl > 8) tl = 8;    // tap 9 zero-padded in A
    int by = tl / 3, bx = tl % 3;
    int p = bx & 1, hb = bx >> 1;
    const char* bb = (const char*)x0s + ((((ql * 3 + by) * 2 + p) * 146) + hb + nn) * 16 + wv * 256;
    short8 B0 = *(const short8*)(bb);
    short8 B1 = *(const short8*)(bb + 1024);
    a00 = mfma16(Ah0, B0, a00); a00 = mfma16(Al0, B0, a00);
    a01 = mfma16(Ah1, B0, a01); a01 = mfma16(Al1, B0, a01);
    a10 = mfma16(Ah0, B1, a10); a10 = mfma16(Al0, B1, a10);
    a11 = mfma16(Ah1, B1, a11); a11 = mfma16(Al1, B1, a11);
    if (wv == 0) {
      short8 B2 = *(const short8*)(bb + 2048);
      a20 = mfma16(Ah0, B2, a20); a20 = mfma16(Al0, B2, a20);
      a21 = mfma16(Ah1, B2, a21); a21 = mfma16(Al1, B2, a21);
    }
  }

  // --- store: Y1T[b][iy][ix][ch32] bf16, ix = f*16+nn, o = h*16+q*4+reg ---
  char* yp = ws + Y1T_OFF + (size_t)(b * 130 + iy) * Y1T_ROWB;
  auto st = [&](int f, f32x4 v0, f32x4 v1) {
    int ix = f * 16 + nn;
    if (ix < 130) {
      uint64_t lo = (uint64_t)packbf(v0[0], v0[1]) | ((uint64_t)packbf(v0[2], v0[3]) << 32);
      uint64_t hi = (uint64_t)packbf(v1[0], v1[1]) | ((uint64_t)packbf(v1[2], v1[3]) << 32);
      *(uint64_t*)(yp + ix * 64 + q * 8) = lo;
      *(uint64_t*)(yp + ix * 64 + 32 + q * 8) = hi;
    }
  };
  st(wv, a00, a01);
  st(wv + 4, a10, a11);
  if (wv == 0) st(8, a20, a21);
}

// ---------------------------------------------------------------------------
// outs_k: raw [0,8192) = out0 (per (b,jy,half), LDS-staged, 5 blk/CU);
//         raw [8192,10240) = out1 (per (b,jy), de-staged direct global).
__global__ __launch_bounds__(256, 5) void outs_k(const float* __restrict__ x0,
                                                 const float* __restrict__ b0,
                                                 const float* __restrict__ b1,
                                                 const float* __restrict__ gg,
                                                 const char* __restrict__ ws,
                                                 float* __restrict__ out) {
  // union LDS: out0 uses 21120 (x0s) + 8448 (y1s) = 29568 B; out1 uses none.
  __shared__ __align__(16) uint16_t smem[2 * 5 * 132 * 8 + 4 * 2 * 66 * 8];
  int raw = blockIdx.x, tid = threadIdx.x;
  int lane = tid & 63, wv = tid >> 6;
  int nn = lane & 15, q = lane >> 4;

  if (raw < 8192) {
    // ===================== out0 =====================
    uint16_t* x0s = smem;                       // [oct 2][row 5][col 132][ch 8]
    uint16_t* y1s = smem + 2 * 5 * 132 * 8;     // [q 4][ry 2][col 66][ch 8]
    int bid = xcd_swz(raw, 1024);
    int b = bid >> 9, jy = (bid >> 1) & 255;
    int jx_base = (bid & 1) << 7;

    { // stage x0: one 16B ch-octet granule per task
      const float* x0b = x0 + (size_t)b * 1048576;
      for (int e = tid; e < 1320; e += 256) {
        int c = e % 132, rr = e / 132, r = rr % 5, oct = rr / 5;
        int gy = jy + r - 2, gx = jx_base + c - 2;
        uint32_t w0 = 0u, w1 = 0u, w2 = 0u, w3 = 0u;
        if ((unsigned)gy < 256u && (unsigned)gx < 256u) {
          const float* p = x0b + (size_t)(oct * 8) * 65536 + gy * 256 + gx;
          w0 = packbf(p[0],      p[65536]);
          w1 = packbf(p[131072], p[196608]);
          w2 = packbf(p[262144], p[327680]);
          w3 = packbf(p[393216], p[458752]);
        }
        *(uint4*)((char*)x0s + (size_t)e * 16) = make_uint4(w0, w1, w2, w3);
      }
    }
    { // stage y1 rows uy+1, uy+2 (bf16 copy into q-planes)
      const char* y1tb = ws + Y1T_OFF;
      int uy = jy >> 1, c0 = jx_base >> 1;
      for (int e = tid; e < 528; e += 256) {
        int qq = e & 3, t = e >> 2, lc = t % 66, ry = t / 66;
        short8 v = *(const short8*)(y1tb +
            ((size_t)(b * 130 + uy + 1 + ry) * 132 + c0 + lc) * 64 + qq * 16);
        *(short8*)((char*)y1s + ((size_t)(qq * 2 + ry) * 66 + lc) * 16) = v;
      }
    }
    __syncthreads();

    int qh = q >> 1, ql = q & 1;
    const char* ab0 = ws + AB0_OFF;
    f32x4 acc[2];
    #pragma unroll
    for (int i = 0; i < 2; ++i) { acc[i][0]=0.f; acc[i][1]=0.f; acc[i][2]=0.f; acc[i][3]=0.f; }

    const uint16_t* xsl = x0s + ql * 5280;   // oct plane (5*132*8)
    const uint16_t* ysl = y1s + q * 1056;    // q plane (2*66*8)
    int pxb = wv * 32 + nn;

    // --- G00 5x5 (center zeroed), tap-pair chunks ---
    #pragma unroll
    for (int c = 0; c < 13; ++c) {
      short8 A = *(const short8*)(ab0 + c * 1024 + lane * 16);
      const int tA = 2 * c;
      const int tB = (2 * c + 1 > 24) ? 24 : 2 * c + 1;
      const int offA = ((tA / 5) * 132 + (tA % 5)) * 8;
      const int offB = ((tB / 5) * 132 + (tB % 5)) * 8;
      int toff = qh ? offB : offA;
      const uint16_t* base = xsl + toff + pxb * 8;
      short8 B0 = *(const short8*)(base);
      short8 B1 = *(const short8*)(base + 128);
      acc[0] = mfma16(A, B0, acc[0]);
      acc[1] = mfma16(A, B1, acc[1]);
    }

    // --- T10^T(Y1): compact cols + parity masks; rows fixed by jy parity ---
    {
      const short8 z8 = {0,0,0,0,0,0,0,0};
      if ((jy & 1) == 0) {
        #pragma unroll
        for (int bx = 0; bx < 3; ++bx) {
          short8 A = *(const short8*)(ab0 + (16 + bx) * 1024 + lane * 16);
          bool keep = (((nn + 3 - bx) & 1) == 0);
          int cb = (nn + 3 - bx) >> 1;
          const uint16_t* base = ysl + (cb + wv * 16) * 8;   // ry = 0
          short8 B0 = *(const short8*)(base);
          short8 B1 = *(const short8*)(base + 64);
          if (!keep) { B0 = z8; B1 = z8; }
          acc[0] = mfma16(A, B0, acc[0]);
          acc[1] = mfma16(A, B1, acc[1]);
        }
      } else {
        #pragma unroll
        for (int s = 0; s < 2; ++s) {          // s=0: by=0 (ry=1); s=1: by=2 (ry=0)
          const int chunkb = s ? 19 : 13;
          const int rybase = s ? 0 : 1;
          #pragma unroll
          for (int bx = 0; bx < 3; ++bx) {
            short8 A = *(const short8*)(ab0 + (chunkb + bx) * 1024 + lane * 16);
            bool keep = (((nn + 3 - bx) & 1) == 0);
            int cb = (nn + 3 - bx) >> 1;
            const uint16_t* base = ysl + (rybase * 66 + cb + wv * 16) * 8;
            short8 B0 = *(const short8*)(base);
            short8 B1 = *(const short8*)(base + 64);
            if (!keep) { B0 = z8; B1 = z8; }
            acc[0] = mfma16(A, B0, acc[0]);
            acc[1] = mfma16(A, B1, acc[1]);
          }
        }
      }
    }

    // --- hollow center: -G10c[jy-parity][px-parity], column-parity masked ---
    {
      const short8 z8 = {0,0,0,0,0,0,0,0};
      short8 A = *(const short8*)(ab0 + (22 + (jy & 1)) * 1024 + lane * 16);
      const uint16_t* base = xsl + (2 * 132 + 2) * 8 + pxb * 8;
      short8 B0 = *(const short8*)(base);
      short8 B1 = *(const short8*)(base + 128);
      bool keep = ((nn & 1) == qh);   // k<16 rows multiply even px, k>=16 odd px
      if (!keep) { B0 = z8; B1 = z8; }
      acc[0] = mfma16(A, B0, acc[0]);
      acc[1] = mfma16(A, B1, acc[1]);
    }

    // --- epilogue: out = b0_hat*g0 - acc ---
    float rs0 = gg[0] / sqrtf(((const float*)(ws + SUM_OFF))[0]);
    #pragma unroll
    for (int i = 0; i < 2; ++i) {
      int px = jx_base + wv * 32 + i * 16 + nn;
      #pragma unroll
      for (int reg = 0; reg < 4; ++reg) {
        int m = q * 4 + reg;
        size_t boff = ((size_t)m * 256 + jy) * 256 + px;
        out[((size_t)(b * 16 + m) * 256 + jy) * 256 + px] = b0[boff] * rs0 - acc[i][reg];
      }
    }
    return;
  }

  // ===================== out1 (de-staged) =====================
  {
    int bid = xcd_swz(raw - 8192, 256);
    int b = bid >> 7, jy = bid & 127;
    const char* ab1 = ws + AB1_OFF;
    // Y1T/X1T are in exact B-frag order: [.][row][col][ch32], 64 B per col,
    // quad q at +q*16.  Per-block footprint (3 y1 rows + 1 x1 row ~ 33 KB)
    // is L1/L2-resident -> direct global reads, no LDS, no barrier.
    const char* yb = ws + Y1T_OFF + ((size_t)(b * 130 + jy) * 132) * 64 + q * 16;
    const char* xb = ws + X1T_OFF + ((size_t)(b * 128 + jy) * 128) * 64 + q * 16;
    f32x4 acc[2][2];
    #pragma unroll
    for (int i = 0; i < 2; ++i)
      #pragma unroll
      for (int h = 0; h < 2; ++h) { acc[i][h][0]=0.f; acc[i][h][1]=0.f; acc[i][h][2]=0.f; acc[i][h][3]=0.f; }

    int pxb = wv * 32 + nn;

    #pragma unroll
    for (int t = 0; t < 9; ++t) {
      const int ay = t / 3, ax = t % 3;
      short8 A0 = *(const short8*)(ab1 + (t * 2 + 0) * 1024 + lane * 16);
      short8 A1 = *(const short8*)(ab1 + (t * 2 + 1) * 1024 + lane * 16);
      const char* base = yb + (size_t)((2 - ay) * 132 + (2 - ax) + pxb) * 64;
      short8 B0 = *(const short8*)(base);
      short8 B1 = *(const short8*)(base + 1024);   // +16 cols
      acc[0][0] = mfma16(A0, B0, acc[0][0]);
      acc[0][1] = mfma16(A1, B0, acc[0][1]);
      acc[1][0] = mfma16(A0, B1, acc[1][0]);
      acc[1][1] = mfma16(A1, B1, acc[1][1]);
    }
    { // -sub1 blockdiag * x1
      short8 A0 = *(const short8*)(ab1 + 18 * 1024 + lane * 16);
      short8 A1 = *(const short8*)(ab1 + 19 * 1024 + lane * 16);
      const char* base = xb + (size_t)pxb * 64;
      short8 B0 = *(const short8*)(base);
      short8 B1 = *(const short8*)(base + 1024);
      acc[0][0] = mfma16(A0, B0, acc[0][0]);
      acc[0][1] = mfma16(A1, B0, acc[0][1]);
      acc[1][0] = mfma16(A0, B1, acc[1][0]);
      acc[1][1] = mfma16(A1, B1, acc[1][1]);
    }

    float rs1 = gg[1] / sqrtf(((const float*)(ws + SUM_OFF))[1]);
    #pragma unroll
    for (int i = 0; i < 2; ++i) {
      int px = wv * 32 + i * 16 + nn;
      #pragma unroll
      for (int h = 0; h < 2; ++h)
        #pragma unroll
        for (int reg = 0; reg < 4; ++reg) {
          int m = h * 16 + q * 4 + reg;
          size_t boff = ((size_t)m * 128 + jy) * 128 + px;
          out[16777216 + ((size_t)(b * 32 + m) * 128 + jy) * 128 + px] = b1[boff] * rs1 - acc[i][h][reg];
        }
    }
  }
}

// ---------------------------------------------------------------------------
extern "C" void kernel_launch(void* const* d_in, const int* in_sizes, int n_in,
                              void* d_out, int out_size, void* d_ws, size_t ws_size,
                              hipStream_t stream) {
  const float* x0  = (const float*)d_in[0];
  const float* x1  = (const float*)d_in[1];
  const float* W00 = (const float*)d_in[2];
  const float* W10 = (const float*)d_in[3];
  const float* W11 = (const float*)d_in[4];
  const float* b0  = (const float*)d_in[5];
  const float* b1  = (const float*)d_in[6];
  const float* g   = (const float*)d_in[7];
  float* out = (float*)d_out;
  char* ws   = (char*)d_ws;

  prep_k<<<2344, 256, 0, stream>>>(x1, W00, W10, W11, b0, b1, ws);
  y1m_k<<<2088, 256, 0, stream>>>(x0, ws);
  outs_k<<<10240, 256, 0, stream>>>(x0, b0, b1, g, ws, out);
}